// Round 1
// baseline (4445.457 us; speedup 1.0000x reference)
//
#include <hip/hip_runtime.h>
#include <cmath>

// Problem constants
#define T_STEPS 512
#define BATCH   64
#define HID     1024
#define INSZ    128
#define ESZ     819
#define OSZ     64

// ws layout (floats):
//  eff_w  [1024*1024]                 @ 0
//  w_ihT  [128*1024]                  @ 1048576
//  hist   [64][512][1024]  ([b][t][h])@ 1179648
//  flags  [256*32] uints              @ 34734080
//  w_fcp  [64*820] (padded w_fc)      @ 34742272
#define WS_EFFW   0
#define WS_WIHT   1048576
#define WS_HIST   1179648
#define WS_FLAGS  34734080
#define WS_WFCP   34742272

// ---------------- prep kernels ----------------
__global__ void prep_effw(const float* __restrict__ w_hh, const float* __restrict__ mask,
                          float* __restrict__ eff) {
    const int i = (blockIdx.x * 256 + threadIdx.x) * 4;
    const float4 w = *(const float4*)(w_hh + i);
    const float4 m = *(const float4*)(mask + i);
    float4 r;
    r.x = fabsf(w.x) * m.x; r.y = fabsf(w.y) * m.y;
    r.z = fabsf(w.z) * m.z; r.w = fabsf(w.w) * m.w;
    *(float4*)(eff + i) = r;
}

__global__ void prep_wihT(const float* __restrict__ w_ih, float* __restrict__ w_ihT) {
    const int idx = blockIdx.x * 256 + threadIdx.x;   // idx = i*1024 + h
    const int i = idx >> 10, h = idx & 1023;
    w_ihT[idx] = w_ih[h * INSZ + i];
}

__global__ void prep_wfc(const float* __restrict__ w_fc, float* __restrict__ w_fcp) {
    const int o = blockIdx.x;
    for (int e = threadIdx.x; e < 820; e += 256)
        w_fcp[o * 820 + e] = (e < ESZ) ? w_fc[o * ESZ + e] : 0.f;
}

// ---------------- input projection: u[b][t][h] = x[t,b,:]@w_ih[h,:] + b_ih[h] ----------------
__global__ void inp_proj(const float* __restrict__ x, const float* __restrict__ w_ihT,
                         const float* __restrict__ b_ih, float* __restrict__ u) {
    __shared__ float xs[INSZ * 64];   // [i][b], 32 KB
    const int t = blockIdx.x, tid = threadIdx.x;
    const float* xt = x + (size_t)t * BATCH * INSZ;
    for (int k = tid * 4; k < BATCH * INSZ; k += 1024) {
        const float4 v = *(const float4*)(xt + k);
        const int b = k >> 7, i = k & 127;
        xs[(i + 0) * 64 + b] = v.x; xs[(i + 1) * 64 + b] = v.y;
        xs[(i + 2) * 64 + b] = v.z; xs[(i + 3) * 64 + b] = v.w;
    }
    __syncthreads();
    for (int hp = 0; hp < 2; ++hp) {
        const int h = hp * 512 + tid * 2;
        const float bi0 = b_ih[h], bi1 = b_ih[h + 1];
        for (int b0 = 0; b0 < 64; b0 += 8) {
            float acc0[8], acc1[8];
#pragma unroll
            for (int bb = 0; bb < 8; ++bb) { acc0[bb] = 0.f; acc1[bb] = 0.f; }
#pragma unroll 4
            for (int i = 0; i < INSZ; ++i) {
                const float2 w2 = *(const float2*)(w_ihT + i * 1024 + h);
                const float4 xa = *(const float4*)(xs + i * 64 + b0);
                const float4 xb = *(const float4*)(xs + i * 64 + b0 + 4);
                const float xv[8] = {xa.x, xa.y, xa.z, xa.w, xb.x, xb.y, xb.z, xb.w};
#pragma unroll
                for (int bb = 0; bb < 8; ++bb) {
                    acc0[bb] = fmaf(w2.x, xv[bb], acc0[bb]);
                    acc1[bb] = fmaf(w2.y, xv[bb], acc1[bb]);
                }
            }
#pragma unroll
            for (int bb = 0; bb < 8; ++bb) {
                float2 r; r.x = acc0[bb] + bi0; r.y = acc1[bb] + bi1;
                *(float2*)(u + ((size_t)(b0 + bb) * T_STEPS + t) * 1024 + h) = r;
            }
        }
    }
}

// ---------------- persistent recurrent scan (cooperative) ----------------
// grid 256 WGs x 256 thr; WG = (bg = blk&7 -> 8 batches, hgrp = blk>>3 -> 32 hidden rows)
// LDS: w_s 32768 floats (swizzled [j][hl]) + pp 8192 floats (prev[8][1024] | part[256][32])
__global__ void __launch_bounds__(256, 1)
rnn_scan(const float* __restrict__ eff_w, const float* __restrict__ u,
         const float* __restrict__ b_hh, const float* __restrict__ alpha,
         float* __restrict__ hist, unsigned* __restrict__ flags) {
    extern __shared__ float smem[];
    float* w_s = smem;            // 32768
    float* pp  = smem + 32768;    // 8192
    const int tid = threadIdx.x, wg = blockIdx.x;
    const int bg = wg & 7, hgrp = wg >> 3;
    const int h0 = hgrp << 5, b0 = bg << 3;

    { // load 32 weight rows, swizzled: logical w[j][hl] -> phys j*32 + (((hl>>2)+j)&7)*4 + (hl&3)
        const int hl = tid >> 3, grp = hl >> 2, l4 = hl & 3;
        const int j0 = (tid & 7) << 7;
        const float* wrow = eff_w + (size_t)(h0 + hl) * 1024;
        for (int j = j0; j < j0 + 128; j += 4) {
            const float4 w4 = *(const float4*)(wrow + j);
            w_s[((j + 0) << 5) + (((grp + j + 0) & 7) << 2) + l4] = w4.x;
            w_s[((j + 1) << 5) + (((grp + j + 1) & 7) << 2) + l4] = w4.y;
            w_s[((j + 2) << 5) + (((grp + j + 2) & 7) << 2) + l4] = w4.z;
            w_s[((j + 3) << 5) + (((grp + j + 3) & 7) << 2) + l4] = w4.w;
        }
    }
    const float a = alpha[0];
    const int r_hl = tid >> 3, r_b = tid & 7;
    const int rh = h0 + r_hl, rb = b0 + r_b;
    const float bias = b_hh[rh];
    const size_t u_base = ((size_t)rb * T_STEPS) * 1024 + rh;
    float* const my_hist = hist + ((size_t)rb * T_STEPS) * 1024 + rh;
    const int hp = tid >> 5, jc = tid & 31;   // compute role: 4h x 8b tile, j-slice
    const int sb = tid >> 5, sj = (tid & 31) << 5;  // staging role
    float state = 0.f;
    __syncthreads();

    for (int t = 0; t < T_STEPS; ++t) {
        const float uval = u[u_base + ((size_t)t << 10)];  // prefetch early
        float red = 0.f;
        if (t > 0) {
            { // stage prev output slice (8 x 1024) into pp = prev[b][j]
                const float* src = hist + ((size_t)(b0 + sb) * T_STEPS + (t - 1)) * 1024 + sj;
                float* dst = pp + (sb << 10) + sj;
#pragma unroll
                for (int k = 0; k < 32; k += 4)
                    *(float4*)(dst + k) = *(const float4*)(src + k);
            }
            __syncthreads();
            float acc[4][8];
#pragma unroll
            for (int i = 0; i < 4; ++i)
#pragma unroll
                for (int b = 0; b < 8; ++b) acc[i][b] = 0.f;
#pragma unroll 2
            for (int jj = 0; jj < 32; ++jj) {
                const int j = (jj << 5) + jc;
                const float4 wv = *(const float4*)&w_s[(j << 5) + (((hp + j) & 7) << 2)];
                float pv[8];
#pragma unroll
                for (int b = 0; b < 8; ++b) pv[b] = pp[(b << 10) + j];
#pragma unroll
                for (int b = 0; b < 8; ++b) {
                    acc[0][b] = fmaf(wv.x, pv[b], acc[0][b]);
                    acc[1][b] = fmaf(wv.y, pv[b], acc[1][b]);
                    acc[2][b] = fmaf(wv.z, pv[b], acc[2][b]);
                    acc[3][b] = fmaf(wv.w, pv[b], acc[3][b]);
                }
            }
            __syncthreads();   // prev consumed; reuse pp as partial buffer
#pragma unroll
            for (int i = 0; i < 4; ++i)
#pragma unroll
                for (int b = 0; b < 8; ++b) {
                    const int oo = ((hp << 2) + i) * 8 + b;
                    pp[(oo << 5) + ((jc + oo) & 31)] = acc[i][b];   // rotated: conflict-free
                }
            __syncthreads();
#pragma unroll
            for (int k = 0; k < 32; ++k)
                red += pp[(tid << 5) + ((k + tid) & 31)];
        }
        const float tot = uval + bias + red;
        state = fmaf(a, tot - state, state);
        const float ov = tanhf(state);
        // write-through agent-scope store: safe for cross-XCD readers (L2s not coherent)
        __hip_atomic_store(my_hist + ((size_t)t << 10), ov, __ATOMIC_RELAXED,
                           __HIP_MEMORY_SCOPE_AGENT);
        asm volatile("s_waitcnt vmcnt(0)" ::: "memory");
        __syncthreads();
        if (tid == 0)
            __hip_atomic_store(flags + (wg << 5), (unsigned)(t + 1), __ATOMIC_RELAXED,
                               __HIP_MEMORY_SCOPE_AGENT);
        if (tid < 64) {  // wave 0 spins on the 32 partner flags of this batch-group
            const unsigned tgt = (unsigned)(t + 1);
            for (;;) {
                unsigned v = tgt;
                if (tid < 32)
                    v = __hip_atomic_load(flags + ((bg + (tid << 3)) << 5), __ATOMIC_RELAXED,
                                          __HIP_MEMORY_SCOPE_AGENT);
                if (__ballot(v >= tgt) == ~0ull) break;
                __builtin_amdgcn_s_sleep(4);
            }
        }
        __syncthreads();
    }
}

// ---------------- rnn_activity copy: act[t][b][h] = hist[b][t][h] ----------------
__global__ void copy_act(const float* __restrict__ hist, float* __restrict__ act) {
    const int t = blockIdx.x >> 6, b = blockIdx.x & 63;
    const float* src = hist + ((size_t)b * T_STEPS + t) * 1024 + threadIdx.x * 4;
    float* dst = act + ((size_t)t * BATCH + b) * 1024 + threadIdx.x * 4;
    *(float4*)dst = *(const float4*)src;
}

// ---------------- final FC: out0[t][b][o] = hist[b][t][:819]@w_fc[o,:] + b_fc[o] ----------------
__global__ void fc_out(const float* __restrict__ hist, const float* __restrict__ w_fcp,
                       const float* __restrict__ b_fc, float* __restrict__ out0) {
    __shared__ float hs[16 * 820];   // 52.5 KB
    const int t = blockIdx.x >> 2, bq = blockIdx.x & 3, tid = threadIdx.x;
    const int b0 = bq << 4;
    for (int r = 0; r < 16; ++r) {
        const float* src = hist + ((size_t)(b0 + r) * T_STEPS + t) * 1024;
        for (int e = tid; e < 820; e += 256) hs[r * 820 + e] = (e < ESZ) ? src[e] : 0.f;
    }
    __syncthreads();
    const int bb = tid >> 4, ol = tid & 15;
    float acc[4] = {0.f, 0.f, 0.f, 0.f};
    const float* hrow = hs + bb * 820;
    for (int e = 0; e < 820; e += 4) {
        const float4 hv = *(const float4*)(hrow + e);
#pragma unroll
        for (int k = 0; k < 4; ++k) {
            const float4 wv = *(const float4*)(w_fcp + (size_t)(ol + (k << 4)) * 820 + e);
            acc[k] += hv.x * wv.x + hv.y * wv.y + hv.z * wv.z + hv.w * wv.w;
        }
    }
    const int b = b0 + bb;
#pragma unroll
    for (int k = 0; k < 4; ++k) {
        const int o = ol + (k << 4);
        out0[((size_t)t * BATCH + b) * OSZ + o] = acc[k] + b_fc[o];
    }
}

extern "C" void kernel_launch(void* const* d_in, const int* in_sizes, int n_in,
                              void* d_out, int out_size, void* d_ws, size_t ws_size,
                              hipStream_t stream) {
    const float* x     = (const float*)d_in[0];
    const float* w_ih  = (const float*)d_in[1];
    const float* b_ih  = (const float*)d_in[2];
    const float* w_hh  = (const float*)d_in[3];
    const float* b_hh  = (const float*)d_in[4];
    const float* w_fc  = (const float*)d_in[5];
    const float* b_fc  = (const float*)d_in[6];
    const float* alpha = (const float*)d_in[7];
    const float* mask  = (const float*)d_in[8];

    float* out  = (float*)d_out;
    float* out0 = out;                                // [512][64][64]
    float* act  = out + (size_t)T_STEPS * BATCH * OSZ; // [512][64][1024]

    float* ws     = (float*)d_ws;
    float* eff_w  = ws + WS_EFFW;
    float* w_ihT  = ws + WS_WIHT;
    float* hist   = ws + WS_HIST;
    unsigned* flags = (unsigned*)(ws + WS_FLAGS);
    float* w_fcp  = ws + WS_WFCP;
    float* u      = act;   // inp_proj lives in d_out's activity region ([b][t][h]), overwritten later

    hipMemsetAsync(flags, 0, 8192 * sizeof(unsigned), stream);
    prep_effw<<<1024, 256, 0, stream>>>(w_hh, mask, eff_w);
    prep_wihT<<<512, 256, 0, stream>>>(w_ih, w_ihT);
    prep_wfc<<<64, 256, 0, stream>>>(w_fc, w_fcp);
    inp_proj<<<512, 256, 0, stream>>>(x, w_ihT, b_ih, u);

    hipFuncSetAttribute(reinterpret_cast<const void*>(rnn_scan),
                        hipFuncAttributeMaxDynamicSharedMemorySize, 163840);
    void* args[] = {(void*)&eff_w, (void*)&u, (void*)&b_hh, (void*)&alpha,
                    (void*)&hist, (void*)&flags};
    hipLaunchCooperativeKernel(reinterpret_cast<const void*>(rnn_scan),
                               dim3(256), dim3(256), args, 163840, stream);

    copy_act<<<32768, 256, 0, stream>>>(hist, act);
    fc_out<<<2048, 256, 0, stream>>>(hist, w_fcp, b_fc, out0);
}